// Round 5
// baseline (848.799 us; speedup 1.0000x reference)
//
#include <hip/hip_runtime.h>
#include <cstdint>
#include <cstddef>

#define BB 128
#define TT 512
#define DD 100
#define HH 100
#define LL 25
#define F_LOG2E 1.44269504088896340736f
#define F_LN2   0.69314718055994530942f

typedef __decltype(__builtin_amdgcn_cvt_pkrtz(0.f, 0.f)) h2_t;
typedef _Float16 v8h __attribute__((ext_vector_type(8)));
typedef float v4f __attribute__((ext_vector_type(4)));

__device__ __forceinline__ unsigned int pk(float x, float y) {
  return __builtin_bit_cast(unsigned int, __builtin_amdgcn_cvt_pkrtz(x, y));
}

__device__ __forceinline__ float fexp2(float x) { return __builtin_amdgcn_exp2f(x); }
__device__ __forceinline__ float flog2(float x) { return __builtin_amdgcn_logf(x); }
__device__ __forceinline__ float frcp(float x)  { return __builtin_amdgcn_rcpf(x); }

__device__ __forceinline__ float sigmoid_f(float x) {
  return frcp(1.f + fexp2(-F_LOG2E * x));
}
__device__ __forceinline__ float tanh_f(float x) {
  float e = fexp2(2.f * F_LOG2E * x);
  return 1.f - 2.f * frcp(e + 1.f);
}

__device__ __forceinline__ float rfl(float v) {
  return __builtin_bit_cast(float,
      __builtin_amdgcn_readfirstlane(__builtin_bit_cast(int, v)));
}

__device__ __forceinline__ void wave_fence() {
#if __has_builtin(__builtin_amdgcn_wave_barrier)
  __builtin_amdgcn_wave_barrier();
#endif
}

// LDS-visibility-only barrier (vmcnt left free): imm 0xC07F.
__device__ __forceinline__ void lds_barrier() {
  __builtin_amdgcn_s_waitcnt(0xC07F);
  __builtin_amdgcn_s_barrier();
}

#define MF(a, b, c) __builtin_amdgcn_mfma_f32_16x16x32_f16(a, b, c, 0, 0, 0)
#define LD8(base, off) __builtin_bit_cast(v8h, *(const uint4*)((base) + (off)))

// h history: [dir][bg][t][b_local 16][112 units pad] fp16 (u>=100 never touched)
__device__ __align__(16) unsigned short g_h[(size_t)2 * 8 * TT * 16 * 112];

// ===========================================================================
// scan16 — MFMA-batched BiLSTM recurrence.
// Grid 16 = (dir 2) x (bgroup 8); 512 thr / 8 waves; 16 batches per block.
// Per step: gates[400 x 16b] = W . [H ; X]^T via mfma_16x16x32_f16, K=256
// (k 0..127 = h pad, 128..255 = x pad). Gate rows in interleaved order
// p = 4*j + g  ->  C-tile lane (l16=batch, quad) holds all 4 gates of unit
// u = 4*ct+quad: activations + c/h update fully lane-local.
// A (weights) in VGPRs (4 tiles x 8 k-chunks x v8h = 128 VGPR).
// B from LDS sbuf[2][16][264] fp16 (row 528B): h double-buffered by parity,
// x ring by parity; x gathered from emb 3 steps ahead (2-step HBM cover).
// h also streamed to g_h (global, 2B stores, vmcnt left open by lds_barrier).
// ===========================================================================
__global__ __launch_bounds__(512, 1) void scan16(
    const int* __restrict__ tok, const float* __restrict__ emb,
    const float* __restrict__ w_ih_f, const float* __restrict__ w_ih_b,
    const float* __restrict__ w_hh_f, const float* __restrict__ w_hh_b,
    const float* __restrict__ b_ih_f, const float* __restrict__ b_hh_f,
    const float* __restrict__ b_ih_b, const float* __restrict__ b_hh_b)
{
  const int tid = threadIdx.x;
  const int dir = blockIdx.x >> 3;
  const int bg  = blockIdx.x & 7;
  const int b0  = bg * 16;
  const float* w_hh = dir ? w_hh_b : w_hh_f;
  const float* w_ih = dir ? w_ih_b : w_ih_f;
  const float* b_ih = dir ? b_ih_b : b_ih_f;
  const float* b_hh = dir ? b_hh_b : b_hh_f;

  __shared__ __align__(16) unsigned short sbuf[2][16][264];  // 16.9 KB

  const int wv   = tid >> 6;
  const int lane = tid & 63;
  const int l16  = lane & 15;
  const int quad = lane >> 4;
  const int c0b  = (25 * wv) >> 3;
  const int c1b  = (25 * (wv + 1)) >> 3;
  const int ncol = c1b - c0b;   // 3 or 4 column tiles (4 units each)

  // ---- A-fragments (weights) + biases ----
  v8h wfr[4][8];
  float bias[4][4];
#pragma unroll
  for (int ci = 0; ci < 4; ++ci) {
    const int ct = (ci < ncol) ? (c0b + ci) : c0b;
    const int prow = 16 * ct + l16;        // interleaved gate index
    const int jA = prow >> 2;              // unit
    const int gA = prow & 3;               // gate
    const float* hr = w_hh + (size_t)(gA * 100 + jA) * HH;
    const float* ir = w_ih + (size_t)(gA * 100 + jA) * DD;
#pragma unroll
    for (int kc = 0; kc < 3; ++kc) {
      const float* wp = hr + kc * 32 + quad * 8;
      float4 va = *(const float4*)(wp);
      float4 vb = *(const float4*)(wp + 4);
      uint4 u;
      u.x = pk(va.x, va.y); u.y = pk(va.z, va.w);
      u.z = pk(vb.x, vb.y); u.w = pk(vb.z, vb.w);
      wfr[ci][kc] = __builtin_bit_cast(v8h, u);
    }
    {
      uint4 u = {0u, 0u, 0u, 0u};
      if (quad == 0) {
        float4 va = *(const float4*)(hr + 96);
        u.x = pk(va.x, va.y); u.y = pk(va.z, va.w);
      }
      wfr[ci][3] = __builtin_bit_cast(v8h, u);
    }
#pragma unroll
    for (int kc = 0; kc < 3; ++kc) {
      const float* wp = ir + kc * 32 + quad * 8;
      float4 va = *(const float4*)(wp);
      float4 vb = *(const float4*)(wp + 4);
      uint4 u;
      u.x = pk(va.x, va.y); u.y = pk(va.z, va.w);
      u.z = pk(vb.x, vb.y); u.w = pk(vb.z, vb.w);
      wfr[ci][4 + kc] = __builtin_bit_cast(v8h, u);
    }
    {
      uint4 u = {0u, 0u, 0u, 0u};
      if (quad == 0) {
        float4 va = *(const float4*)(ir + 96);
        u.x = pk(va.x, va.y); u.y = pk(va.z, va.w);
      }
      wfr[ci][7] = __builtin_bit_cast(v8h, u);
    }
    const int u_own = 4 * ct + quad;       // C-side unit of this lane
#pragma unroll
    for (int r = 0; r < 4; ++r)
      bias[ci][r] = b_ih[r * 100 + u_own] + b_hh[r * 100 + u_own];
  }

  // ---- loader mapping: 400 threads, (row = batch, seg = 4-dim chunk) ----
  const bool ldr = tid < 400;
  const int lrow = tid / 25;
  const int lseg = tid - 25 * lrow;

  unsigned short* ghb = g_h + (size_t)(dir * 8 + bg) * TT * 16 * 112;

  // ---- prologue: zero buffers, stage x(0), issue x(1)/x(2) ----
  for (int i = tid; i < 4224; i += 512) ((unsigned int*)sbuf)[i] = 0u;
  float4 xA = {0, 0, 0, 0}, xB = {0, 0, 0, 0};
  if (ldr) {
    int ta = dir ? (TT - 1) : 0;
    int tk = tok[(b0 + lrow) * TT + ta];
    xA = *(const float4*)(emb + (size_t)tk * DD + lseg * 4);
  }
  __syncthreads();
  if (ldr) {
    uint2 w; w.x = pk(xA.x, xA.y); w.y = pk(xA.z, xA.w);
    *(uint2*)(&sbuf[0][lrow][128 + lseg * 4]) = w;
    int ta1 = dir ? (TT - 2) : 1;
    int tk1 = tok[(b0 + lrow) * TT + ta1];
    xA = *(const float4*)(emb + (size_t)tk1 * DD + lseg * 4);
    int ta2 = dir ? (TT - 3) : 2;
    int tk2 = tok[(b0 + lrow) * TT + ta2];
    xB = *(const float4*)(emb + (size_t)tk2 * DD + lseg * 4);
  }
  __syncthreads();

  float cst[4] = {0.f, 0.f, 0.f, 0.f};

#define SSTEP(T, XS)                                                        \
  {                                                                        \
    const int p = (T) & 1;                                                 \
    const int ta = dir ? (TT - 1 - (T)) : (T);                             \
    const unsigned short* bh = &sbuf[1 - p][l16][0];                       \
    const unsigned short* bx = &sbuf[p][l16][128];                         \
    v8h f0 = LD8(bh, 0 + quad * 8);                                        \
    v8h f1 = LD8(bh, 32 + quad * 8);                                       \
    v8h f2 = LD8(bh, 64 + quad * 8);                                       \
    v8h f3 = LD8(bh, 96 + quad * 8);                                       \
    v8h f4 = LD8(bx, 0 + quad * 8);                                        \
    v8h f5 = LD8(bx, 32 + quad * 8);                                       \
    v8h f6 = LD8(bx, 64 + quad * 8);                                       \
    v8h f7 = LD8(bx, 96 + quad * 8);                                       \
    _Pragma("unroll")                                                      \
    for (int ci = 0; ci < 4; ++ci) {                                       \
      if (ci >= ncol) break;                                               \
      v4f acc = {0.f, 0.f, 0.f, 0.f};                                      \
      acc = MF(wfr[ci][0], f0, acc);                                       \
      acc = MF(wfr[ci][1], f1, acc);                                       \
      acc = MF(wfr[ci][2], f2, acc);                                       \
      acc = MF(wfr[ci][3], f3, acc);                                       \
      acc = MF(wfr[ci][4], f4, acc);                                       \
      acc = MF(wfr[ci][5], f5, acc);                                       \
      acc = MF(wfr[ci][6], f6, acc);                                       \
      acc = MF(wfr[ci][7], f7, acc);                                       \
      float iv = sigmoid_f(acc[0] + bias[ci][0]);                          \
      float fv = sigmoid_f(acc[1] + bias[ci][1]);                          \
      float gv = tanh_f(acc[2] + bias[ci][2]);                             \
      float ov = sigmoid_f(acc[3] + bias[ci][3]);                          \
      cst[ci] = fmaf(fv, cst[ci], iv * gv);                                \
      float hv = ov * tanh_f(cst[ci]);                                     \
      unsigned short hh = __builtin_bit_cast(unsigned short, (__fp16)hv);  \
      const int u_own = 4 * (c0b + ci) + quad;                             \
      sbuf[p][l16][u_own] = hh;                                            \
      ghb[((size_t)ta * 16 + l16) * 112 + u_own] = hh;                     \
    }                                                                      \
    if (ldr) {                                                             \
      if ((T) + 1 < TT) {                                                  \
        uint2 w; w.x = pk(XS.x, XS.y); w.y = pk(XS.z, XS.w);               \
        *(uint2*)(&sbuf[1 - p][lrow][128 + lseg * 4]) = w;                 \
      }                                                                    \
      int s = ((T) + 3 < TT) ? (T) + 3 : (TT - 1);                         \
      int tas = dir ? (TT - 1 - s) : s;                                    \
      int tk = tok[(b0 + lrow) * TT + tas];                                \
      XS = *(const float4*)(emb + (size_t)tk * DD + lseg * 4);             \
    }                                                                      \
    lds_barrier();                                                         \
  }

  for (int t2 = 0; t2 < TT; t2 += 2) {
    SSTEP(t2, xA)
    SSTEP(t2 + 1, xB)
  }
#undef SSTEP
}

// ===========================================================================
// emit_gemm — summed emissions em[b][t][25] = h_f.Wf + h_b.Wb + b_tag.
// Grid 512 = (bg 8) x (t-chunk 64, 8 steps each); 512 thr; wave w -> step w.
// Same MFMA pattern: A = w_tag label rows, B = H^T fragments from LDS.
// ===========================================================================
__global__ __launch_bounds__(512, 1) void emit_gemm(
    const float* __restrict__ w_tag, const float* __restrict__ b_tag,
    float* __restrict__ em)
{
  const int tid = threadIdx.x;
  const int bg  = blockIdx.x & 7;
  const int tc  = blockIdx.x >> 3;
  const int t0  = tc * 8;
  const int b0  = bg * 16;

  __shared__ __align__(16) unsigned short hb[8][2][16][136];  // 69.6 KB

  const int wv   = tid >> 6;
  const int lane = tid & 63;
  const int l16  = lane & 15;
  const int quad = lane >> 4;

  // ---- A-fragments: w_tag rows (2 label tiles x 2 dirs x 4 k-chunks) ----
  v8h wfr[2][2][4];
  float bo[2][4];
#pragma unroll
  for (int lt = 0; lt < 2; ++lt) {
    const int label = lt * 16 + l16;
    const bool valid = label < LL;
#pragma unroll
    for (int d = 0; d < 2; ++d) {
      const float* wr = w_tag + (size_t)(valid ? label : 0) * 200 + d * 100;
#pragma unroll
      for (int kc = 0; kc < 3; ++kc) {
        uint4 u = {0u, 0u, 0u, 0u};
        if (valid) {
          const float* wp = wr + kc * 32 + quad * 8;
          float4 va = *(const float4*)(wp);
          float4 vb = *(const float4*)(wp + 4);
          u.x = pk(va.x, va.y); u.y = pk(va.z, va.w);
          u.z = pk(vb.x, vb.y); u.w = pk(vb.z, vb.w);
        }
        wfr[lt][d][kc] = __builtin_bit_cast(v8h, u);
      }
      {
        uint4 u = {0u, 0u, 0u, 0u};
        if (valid && quad == 0) {
          float4 va = *(const float4*)(wr + 96);
          u.x = pk(va.x, va.y); u.y = pk(va.z, va.w);
        }
        wfr[lt][d][3] = __builtin_bit_cast(v8h, u);
      }
    }
#pragma unroll
    for (int r = 0; r < 4; ++r) {
      int lab = lt * 16 + 4 * quad + r;
      bo[lt][r] = (lab < LL) ? b_tag[lab] : 0.f;
    }
  }

  // ---- zero the u>=100 tail of hb (rows 256 x 36 shorts) ----
  for (int i = tid; i < 256 * 18; i += 512) {
    int r = i / 18, k = i - 18 * r;
    *(unsigned int*)((char*)hb + r * 272 + 200 + k * 4) = 0u;
  }
  __syncthreads();

  // ---- stage h rows from g_h: 256 rows x 200B (12 x 16B + 1 x 8B) ----
  for (int i = tid; i < 256 * 13; i += 512) {
    int row = i / 13, cp = i - 13 * row;
    int tloc = row >> 5, d = (row >> 4) & 1, b = row & 15;
    const char* src = (const char*)(g_h +
        (size_t)(d * 8 + bg) * TT * 16 * 112 +
        ((size_t)(t0 + tloc) * 16 + b) * 112);
    char* dst = (char*)hb + row * 272;
    if (cp < 12)
      *(uint4*)(dst + cp * 16) = *(const uint4*)(src + cp * 16);
    else
      *(uint2*)(dst + 192) = *(const uint2*)(src + 192);
  }
  __syncthreads();

  // ---- compute: wave wv handles step t0+wv ----
  v8h fh[2][4];
#pragma unroll
  for (int d = 0; d < 2; ++d)
#pragma unroll
    for (int kc = 0; kc < 4; ++kc)
      fh[d][kc] = LD8(&hb[wv][d][l16][0], kc * 32 + quad * 8);

#pragma unroll
  for (int lt = 0; lt < 2; ++lt) {
    v4f acc = {0.f, 0.f, 0.f, 0.f};
#pragma unroll
    for (int d = 0; d < 2; ++d) {
      acc = MF(wfr[lt][d][0], fh[d][0], acc);
      acc = MF(wfr[lt][d][1], fh[d][1], acc);
      acc = MF(wfr[lt][d][2], fh[d][2], acc);
      acc = MF(wfr[lt][d][3], fh[d][3], acc);
    }
#pragma unroll
    for (int r = 0; r < 4; ++r) {
      int lab = lt * 16 + 4 * quad + r;
      if (lab < LL)
        em[((size_t)(b0 + l16) * TT + (t0 + wv)) * LL + lab] = acc[r] + bo[lt][r];
    }
  }
}

// ===========================================================================
// CRF — parallel chunked scan (verified structure; now reads summed em).
// ===========================================================================
#define CHN  8
#define CLEN 64
__device__ __align__(16) float g_PT[(size_t)BB * CHN * LL * 28];  // 2.87 MB

__global__ __launch_bounds__(128, 2) void crf_chunks(
    const float* __restrict__ em, const float* __restrict__ trans)
{
  const int tid = threadIdx.x;
  const int b   = blockIdx.x >> 3;
  const int c   = blockIdx.x & 7;
  const int ts  = c * CLEN;

  __shared__ __align__(16) float Al[2][LL][28];   // double-buffered A
  __shared__ __align__(16) float el[CLEN][32];    // e_t[j] = exp(em_t[j])

  // ---- stage e rows (2 threads per time step) ----
  {
    const int row  = tid >> 1;        // 0..63
    const int half = tid & 1;
    const int jb   = half ? 13 : 0;
    const int nj   = half ? 12 : 13;
    const float* pe = em + ((size_t)b * TT + ts + row) * LL;
    for (int q = 0; q < nj; ++q) {
      int jj = jb + q;
      el[row][jj] = fexp2(pe[jj] * F_LOG2E);
    }
  }

  const bool lact = tid < 125;
  const int i  = tid / 5;          // output row 0..24
  const int jg = tid - 5 * i;      // col group 0..4
  const int j0 = 5 * jg;

  // ---- E' = exp(T)*2^-5, columns j0..j0+4, in registers ----
  float E[25][5];
  if (lact) {
#pragma unroll
    for (int k = 0; k < 25; ++k) {
      const float* tr = trans + k * 25 + j0;
#pragma unroll
      for (int u = 0; u < 5; ++u)
        E[k][u] = fexp2(tr[u] * F_LOG2E - 5.f);
    }
#pragma unroll
    for (int u = 0; u < 5; ++u)
      Al[0][i][j0 + u] = (i == j0 + u) ? 1.f : 0.f;
  }
  __syncthreads();

  int p = 0;
  const int s0 = (c == 0) ? 1 : 0;   // chunk 0 covers t = 1..63
  for (int st = s0; st < CLEN; ++st) {
    if (lact) {
      const float* ar = &Al[p][i][0];
      float4 q0 = *(const float4*)(ar);
      float4 q1 = *(const float4*)(ar + 4);
      float4 q2 = *(const float4*)(ar + 8);
      float4 q3 = *(const float4*)(ar + 12);
      float4 q4 = *(const float4*)(ar + 16);
      float4 q5 = *(const float4*)(ar + 20);
      float a24 = ar[24];
      float e0 = el[st][j0];
      float e1 = el[st][j0 + 1];
      float e2 = el[st][j0 + 2];
      float e3 = el[st][j0 + 3];
      float e4 = el[st][j0 + 4];
      float av[25] = {q0.x, q0.y, q0.z, q0.w, q1.x, q1.y, q1.z, q1.w,
                      q2.x, q2.y, q2.z, q2.w, q3.x, q3.y, q3.z, q3.w,
                      q4.x, q4.y, q4.z, q4.w, q5.x, q5.y, q5.z, q5.w, a24};
      float c0 = 0.f, c1 = 0.f, c2 = 0.f, c3 = 0.f, c4 = 0.f;
#pragma unroll
      for (int k = 0; k < 25; ++k) {
        float avk = av[k];
        c0 = fmaf(avk, E[k][0], c0);
        c1 = fmaf(avk, E[k][1], c1);
        c2 = fmaf(avk, E[k][2], c2);
        c3 = fmaf(avk, E[k][3], c3);
        c4 = fmaf(avk, E[k][4], c4);
      }
      float* wr = &Al[p ^ 1][i][j0];
      wr[0] = c0 * e0; wr[1] = c1 * e1; wr[2] = c2 * e2;
      wr[3] = c3 * e3; wr[4] = c4 * e4;
    }
    __syncthreads();
    p ^= 1;
  }

  if (lact) {
    const size_t base = ((size_t)(b * CHN + c)) * LL;
#pragma unroll
    for (int u = 0; u < 5; ++u)
      g_PT[(base + (j0 + u)) * 28 + i] = Al[p][i][j0 + u];
  }
}

__global__ __launch_bounds__(128) void crf_combine(
    const float* __restrict__ em,
    const int* __restrict__ tags, const int* __restrict__ lengths,
    const float* __restrict__ trans,
    const float* __restrict__ startt, const float* __restrict__ endt,
    float* __restrict__ out)
{
  const int tid = threadIdx.x;
  const int b   = blockIdx.x;

  __shared__ __align__(16) float Vs[28];

  if (tid < 64) {
    // -------- wave 0: logZ via chunk-matrix chain --------
    const int lane = tid;
    const int j = (lane < LL) ? lane : 0;
    const float* e0p = em + (size_t)b * TT * LL;
    float v = fexp2((startt[j] + e0p[j]) * F_LOG2E);  // alpha0
    float C = 0.f;
    for (int c = 0; c < CHN; ++c) {
      if (lane < LL) Vs[lane] = v;
      wave_fence();
      float4 s0 = *(const float4*)(Vs);
      float4 s1 = *(const float4*)(Vs + 4);
      float4 s2 = *(const float4*)(Vs + 8);
      float4 s3 = *(const float4*)(Vs + 12);
      float4 s4 = *(const float4*)(Vs + 16);
      float4 s5 = *(const float4*)(Vs + 20);
      float s24 = Vs[24];
      wave_fence();
      const float* pr = g_PT + ((size_t)(b * CHN + c) * LL + j) * 28;
      float4 p0 = *(const float4*)(pr);
      float4 p1 = *(const float4*)(pr + 4);
      float4 p2 = *(const float4*)(pr + 8);
      float4 p3 = *(const float4*)(pr + 12);
      float4 p4 = *(const float4*)(pr + 16);
      float4 p5 = *(const float4*)(pr + 20);
      float p24 = pr[24];
      float nv = s0.x * p0.x;
      nv = fmaf(s0.y, p0.y, nv); nv = fmaf(s0.z, p0.z, nv); nv = fmaf(s0.w, p0.w, nv);
      nv = fmaf(s1.x, p1.x, nv); nv = fmaf(s1.y, p1.y, nv);
      nv = fmaf(s1.z, p1.z, nv); nv = fmaf(s1.w, p1.w, nv);
      nv = fmaf(s2.x, p2.x, nv); nv = fmaf(s2.y, p2.y, nv);
      nv = fmaf(s2.z, p2.z, nv); nv = fmaf(s2.w, p2.w, nv);
      nv = fmaf(s3.x, p3.x, nv); nv = fmaf(s3.y, p3.y, nv);
      nv = fmaf(s3.z, p3.z, nv); nv = fmaf(s3.w, p3.w, nv);
      nv = fmaf(s4.x, p4.x, nv); nv = fmaf(s4.y, p4.y, nv);
      nv = fmaf(s4.z, p4.z, nv); nv = fmaf(s4.w, p4.w, nv);
      nv = fmaf(s5.x, p5.x, nv); nv = fmaf(s5.y, p5.y, nv);
      nv = fmaf(s5.z, p5.z, nv); nv = fmaf(s5.w, p5.w, nv);
      nv = fmaf(s24, p24, nv);
      float nv0 = rfl(nv);
      int k = ((__builtin_bit_cast(int, nv0) >> 23) & 255) - 127;
      k = (k > 100) ? 100 : ((k < -100) ? -100 : k);
      float scl = __builtin_bit_cast(float, (127 - k) << 23);
      v = nv * scl;
      C += (float)k;
    }
    float term = (lane < LL) ? v * fexp2(endt[j] * F_LOG2E) : 0.f;
    for (int o = 32; o > 0; o >>= 1) term += __shfl_down(term, o);
    if (lane == 0)
      atomicAdd(out, (flog2(term) + C + 5.f * 511.f) * F_LN2);
  } else {
    // -------- wave 1: gold path score --------
    const int lane = tid & 63;
    const int len = lengths[b];
    float acc = 0.f;
#pragma unroll
    for (int k = 0; k < 8; ++k) {
      int t = k * 64 + lane;
      int tg = tags[b * TT + t];
      size_t ei = ((size_t)b * TT + t) * LL + tg;
      float e = em[ei];
      float term;
      if (t == 0) term = startt[tg] + e;
      else        term = trans[tags[b * TT + t - 1] * LL + tg] + e;
      if (t == len - 1) term += endt[tg];
      if (t < len) acc += term;
    }
    for (int o = 32; o > 0; o >>= 1) acc += __shfl_down(acc, o);
    if (lane == 0) atomicAdd(out, -acc);
  }
}

extern "C" void kernel_launch(void* const* d_in, const int* in_sizes, int n_in,
                              void* d_out, int out_size, void* d_ws, size_t ws_size,
                              hipStream_t stream) {
  const int*   tok   = (const int*)d_in[0];
  const int*   tags  = (const int*)d_in[1];
  const int*   lens  = (const int*)d_in[2];
  const float* emb   = (const float*)d_in[3];
  const float* wif   = (const float*)d_in[4];
  const float* whf   = (const float*)d_in[5];
  const float* bif   = (const float*)d_in[6];
  const float* bhf   = (const float*)d_in[7];
  const float* wib   = (const float*)d_in[8];
  const float* whb   = (const float*)d_in[9];
  const float* bib   = (const float*)d_in[10];
  const float* bhb   = (const float*)d_in[11];
  const float* wtag  = (const float*)d_in[12];
  const float* btag  = (const float*)d_in[13];
  const float* trans = (const float*)d_in[14];
  const float* st    = (const float*)d_in[15];
  const float* en    = (const float*)d_in[16];

  float* em = (float*)d_ws;   // 128*512*25*4 = 6,553,600 B (summed emissions)

  hipMemsetAsync(d_out, 0, sizeof(float), stream);

  scan16<<<16, 512, 0, stream>>>(tok, emb, wif, wib, whf, whb,
                                 bif, bhf, bib, bhb);
  emit_gemm<<<512, 512, 0, stream>>>(wtag, btag, em);
  crf_chunks<<<BB * CHN, 128, 0, stream>>>(em, trans);
  crf_combine<<<BB, 128, 0, stream>>>(em, tags, lens, trans, st, en,
                                      (float*)d_out);
}

// Round 6
// 492.218 us; speedup vs baseline: 1.7244x; 1.7244x over previous
//
#include <hip/hip_runtime.h>
#include <cstdint>
#include <cstddef>

#define BB 128
#define TT 512
#define DD 100
#define HH 100
#define LL 25
#define TS 32
#define NTILE 16
#define F_LOG2E 1.44269504088896340736f
#define F_LN2   0.69314718055994530942f

typedef __decltype(__builtin_amdgcn_cvt_pkrtz(0.f, 0.f)) h2_t;
typedef _Float16 v8h __attribute__((ext_vector_type(8)));
typedef float v4f __attribute__((ext_vector_type(4)));

__device__ __forceinline__ h2_t bc_h2(unsigned int u) {
  return __builtin_bit_cast(h2_t, u);
}
__device__ __forceinline__ unsigned int pk(float x, float y) {
  return __builtin_bit_cast(unsigned int, __builtin_amdgcn_cvt_pkrtz(x, y));
}
// round-to-nearest-even fp16 pack (matches scalar (__fp16) h-store numerics)
__device__ __forceinline__ unsigned int pk_rte(float x, float y) {
  unsigned short a = __builtin_bit_cast(unsigned short, (__fp16)x);
  unsigned short c = __builtin_bit_cast(unsigned short, (__fp16)y);
  return (unsigned int)a | ((unsigned int)c << 16);
}

__device__ __forceinline__ float fdot2(h2_t a, h2_t b, float c) {
#if __has_builtin(__builtin_amdgcn_fdot2)
  return __builtin_amdgcn_fdot2(a, b, c, false);
#else
  return c + (float)a[0] * (float)b[0] + (float)a[1] * (float)b[1];
#endif
}

__device__ __forceinline__ float fexp2(float x) { return __builtin_amdgcn_exp2f(x); }
__device__ __forceinline__ float flog2(float x) { return __builtin_amdgcn_logf(x); }
__device__ __forceinline__ float frcp(float x)  { return __builtin_amdgcn_rcpf(x); }

__device__ __forceinline__ float sigmoid_f(float x) {
  return frcp(1.f + fexp2(-F_LOG2E * x));
}
__device__ __forceinline__ float tanh_f(float x) {
  float e = fexp2(2.f * F_LOG2E * x);
  return 1.f - 2.f * frcp(e + 1.f);
}

template <int CTRL>
__device__ __forceinline__ float qadd(float v) {
#if __has_builtin(__builtin_amdgcn_mov_dpp)
  int m = __builtin_amdgcn_mov_dpp(__builtin_bit_cast(int, v), CTRL, 0xF, 0xF, true);
  return v + __builtin_bit_cast(float, m);
#else
  int x = (CTRL == 177) ? 1 : 2;
  return v + __shfl_xor(v, x);
#endif
}

template <int LANE>
__device__ __forceinline__ float qbcast(float v) {
#if __has_builtin(__builtin_amdgcn_mov_dpp)
  int m = __builtin_amdgcn_mov_dpp(__builtin_bit_cast(int, v), LANE * 0x55, 0xF, 0xF, true);
  return __builtin_bit_cast(float, m);
#else
  return __shfl(v, (threadIdx.x & 63 & ~3) + LANE);
#endif
}

__device__ __forceinline__ float rfl(float v) {
  return __builtin_bit_cast(float,
      __builtin_amdgcn_readfirstlane(__builtin_bit_cast(int, v)));
}

__device__ __forceinline__ void wave_fence() {
#if __has_builtin(__builtin_amdgcn_wave_barrier)
  __builtin_amdgcn_wave_barrier();
#endif
}

// LDS-visibility-only barrier (vmcnt left free): imm 0xC07F.
__device__ __forceinline__ void lds_barrier() {
  __builtin_amdgcn_s_waitcnt(0xC07F);
  __builtin_amdgcn_s_barrier();
}

#define MF(a, b, c) __builtin_amdgcn_mfma_f32_16x16x32_f16(a, b, c, 0, 0, 0)
#define LD8(base, off) __builtin_bit_cast(v8h, *(const uint4*)((base) + (off)))

// gate inputs gin[dir][b][t][400] fp16, permuted p = 4*j + g order  (105 MB)
__device__ __align__(16) unsigned short g_gin[(size_t)2 * BB * TT * 400];
// hidden states h[dir][b][t][50] packed fp16-pairs                  (26 MB)
__device__ __align__(16) unsigned int g_h2[(size_t)2 * BB * TT * 50];

// ===========================================================================
// gin_gemm — precompute gin = x . W_ih^T for all (dir,b,t). v4's burst,
// standalone: per tile stage x -> xlds, MFMA into gt (permuted 2B stores),
// then coalesced b128 copy gt -> g_gin.
// ===========================================================================
__global__ __launch_bounds__(512, 1) void gin_gemm(
    const int* __restrict__ tok, const float* __restrict__ emb,
    const float* __restrict__ w_ih_f, const float* __restrict__ w_ih_b)
{
  const int tid = threadIdx.x;
  const int b   = blockIdx.x & 127;
  const int dir = blockIdx.x >> 7;
  const float* w_ih = dir ? w_ih_b : w_ih_f;

  __shared__ __align__(16) unsigned int xlds[TS * 68];         // 8.7 KB
  __shared__ __align__(16) unsigned short gt[TS * 400];        // 25.6 KB

  const int wv   = tid >> 6;
  const int lane = tid & 63;
  const int l16  = lane & 15;
  const int quad = lane >> 4;
  const int c0b  = (25 * wv) >> 3;
  const int c1b  = (25 * (wv + 1)) >> 3;
  const int ncol = c1b - c0b;   // 3 or 4

  // ---- B fragments of w_ih in registers (v4 verbatim) ----
  v8h bfr[4][4];
  int pcol[4];
#pragma unroll
  for (int ci = 0; ci < 4; ++ci) {
    const int cc = (ci < ncol) ? (c0b + ci) : c0b;
    const int n  = 16 * cc + l16;
    const float* wr = w_ih + (size_t)n * DD;
#pragma unroll
    for (int f = 0; f < 3; ++f) {
      const float* wp = wr + f * 32 + quad * 8;
      float4 va = *(const float4*)(wp);
      float4 vb = *(const float4*)(wp + 4);
      uint4 u;
      u.x = pk(va.x, va.y); u.y = pk(va.z, va.w);
      u.z = pk(vb.x, vb.y); u.w = pk(vb.z, vb.w);
      bfr[ci][f] = __builtin_bit_cast(v8h, u);
    }
    {
      uint4 u = {0u, 0u, 0u, 0u};
      if (quad == 0) {
        float4 va = *(const float4*)(wr + 96);
        u.x = pk(va.x, va.y); u.y = pk(va.z, va.w);
      }
      bfr[ci][3] = __builtin_bit_cast(v8h, u);
    }
    const int qn = (n * 41) >> 12;            // n/100 for n<400
    pcol[ci] = ((n - 100 * qn) << 2) + qn;    // store permutation
  }

  // ---- xlds K-pad zero ----
  for (int i = tid; i < TS * 18; i += 512) {
    int row = i / 18;
    int d = i - row * 18;
    xlds[row * 68 + 50 + d] = 0u;
  }

  // ---- x staging mapping ----
  const int tprow = tid / 13;
  const int tps   = tid - 13 * tprow;
  const bool tp_act = tid < 416;

  float4 xa = {0, 0, 0, 0}, xb = {0, 0, 0, 0};
  if (tp_act) {
    int ii = tprow;
    int tt = dir ? (TT - 1 - ii) : ii;
    int tk = tok[b * TT + tt];
    const float* xp = emb + (size_t)tk * DD + 8 * tps;
    xa = *(const float4*)xp;
    if (tps < 12) xb = *(const float4*)(xp + 4);
  }

  unsigned short* gout_g = g_gin + (size_t)(dir * BB + b) * TT * 400;
  __syncthreads();

  for (int T = 0; T < NTILE; ++T) {
    if (tp_act) {
      unsigned int* xr = xlds + tprow * 68 + 4 * tps;
      if (tps < 12) {
        uint4 u;
        u.x = pk(xa.x, xa.y); u.y = pk(xa.z, xa.w);
        u.z = pk(xb.x, xb.y); u.w = pk(xb.z, xb.w);
        *(uint4*)xr = u;
      } else {
        xr[0] = pk(xa.x, xa.y);
        xr[1] = pk(xa.z, xa.w);
      }
    }
    __syncthreads();

    {
      v8h af[2][4];
#pragma unroll
      for (int rg = 0; rg < 2; ++rg)
#pragma unroll
        for (int f = 0; f < 4; ++f)
          af[rg][f] = __builtin_bit_cast(v8h,
              *(const uint4*)(xlds + (rg * 16 + l16) * 68 + f * 16 + quad * 4));

      if (tp_act && T + 1 < NTILE) {
        int ii = (T + 1) * TS + tprow;
        int tt = dir ? (TT - 1 - ii) : ii;
        int tk = tok[b * TT + tt];
        const float* xp = emb + (size_t)tk * DD + 8 * tps;
        xa = *(const float4*)xp;
        if (tps < 12) xb = *(const float4*)(xp + 4);
      }

      __fp16* gout = (__fp16*)gt;
#pragma unroll
      for (int ci = 0; ci < 4; ++ci) {
        if (ci >= ncol) break;
        const int p = pcol[ci];
#pragma unroll
        for (int rg = 0; rg < 2; ++rg) {
          v4f acc = {0.f, 0.f, 0.f, 0.f};
          acc = MF(af[rg][0], bfr[ci][0], acc);
          acc = MF(af[rg][1], bfr[ci][1], acc);
          acc = MF(af[rg][2], bfr[ci][2], acc);
          acc = MF(af[rg][3], bfr[ci][3], acc);
          const int rowb = rg * 16 + quad * 4;
#pragma unroll
          for (int r = 0; r < 4; ++r)
            gout[(rowb + r) * 400 + p] = (__fp16)acc[r];
        }
      }
    }
    __syncthreads();

    // coalesced copy-out: 32 rows x 800B = 1600 uint4
    {
      const uint4* s = (const uint4*)gt;
      uint4* d = (uint4*)(gout_g + (size_t)T * TS * 400);
      for (int i = tid; i < 1600; i += 512) d[i] = s[i];
    }
    __syncthreads();
  }
}

// ===========================================================================
// scan_lean — recurrence only. 256 blocks (b,dir) x 256 thr (4 waves).
// v4 SCAN2 numerics bit-identical. gin rows register-rotated from global
// (prefetch 2 steps ahead); one lgkm-only barrier per step; h -> hls + g_h2.
// ===========================================================================
__global__ __launch_bounds__(256, 1) void scan_lean(
    const float* __restrict__ w_hh_f, const float* __restrict__ w_hh_b,
    const float* __restrict__ b_ih_f, const float* __restrict__ b_hh_f,
    const float* __restrict__ b_ih_b, const float* __restrict__ b_hh_b)
{
  const int tid = threadIdx.x;
  const int b   = blockIdx.x & 127;
  const int dir = blockIdx.x >> 7;
  const float* w_hh = dir ? w_hh_b : w_hh_f;
  const float* b_ih = dir ? b_ih_b : b_ih_f;
  const float* b_hh = dir ? b_hh_b : b_hh_f;

  __shared__ __align__(16) unsigned int hls0[56];
  __shared__ __align__(16) unsigned int hls1[56];

  const bool uact = tid < 200;
  const int j  = tid >> 1;
  const int s2 = tid & 1;

  h2_t wG0[25], wG1[25], wG2[25], wG3[25];
  float bias0 = 0.f, bias1 = 0.f, bias2 = 0.f, bias3 = 0.f;
  if (uact) {
    const float* r0 = w_hh + (size_t)(0 * 100 + j) * HH + 50 * s2;
    const float* r1 = w_hh + (size_t)(1 * 100 + j) * HH + 50 * s2;
    const float* r2 = w_hh + (size_t)(2 * 100 + j) * HH + 50 * s2;
    const float* r3 = w_hh + (size_t)(3 * 100 + j) * HH + 50 * s2;
#pragma unroll
    for (int d = 0; d < 25; ++d) {
      float2 v0 = *(const float2*)(r0 + 2 * d);
      float2 v1 = *(const float2*)(r1 + 2 * d);
      float2 v2 = *(const float2*)(r2 + 2 * d);
      float2 v3 = *(const float2*)(r3 + 2 * d);
      wG0[d] = __builtin_amdgcn_cvt_pkrtz(v0.x, v0.y);
      wG1[d] = __builtin_amdgcn_cvt_pkrtz(v1.x, v1.y);
      wG2[d] = __builtin_amdgcn_cvt_pkrtz(v2.x, v2.y);
      wG3[d] = __builtin_amdgcn_cvt_pkrtz(v3.x, v3.y);
    }
    bias0 = b_ih[j]       + b_hh[j];
    bias1 = b_ih[100 + j] + b_hh[100 + j];
    bias2 = b_ih[200 + j] + b_hh[200 + j];
    bias3 = b_ih[300 + j] + b_hh[300 + j];
  }

  if (tid < 56) { hls0[tid] = 0u; hls1[tid] = 0u; }

  const unsigned short* gbase = g_gin + (size_t)(dir * BB + b) * TT * 400;
  unsigned int* ghb = g_h2 + (size_t)(dir * BB + b) * TT * 50;

  uint2 ga = {0u, 0u}, gb = {0u, 0u};
  if (uact) {
    ga = ((const uint2*)(gbase))[j];
    gb = ((const uint2*)(gbase + 400))[j];
  }
  float c = 0.f;
  __syncthreads();

#define SD2(d, hw) { h2_t hv = bc_h2(hw);                                  \
  p0 = fdot2(wG0[d], hv, p0); p1 = fdot2(wG1[d], hv, p1);                  \
  p2 = fdot2(wG2[d], hv, p2); p3 = fdot2(wG3[d], hv, p3); }

#define SSTEP(T, GREG, HRD, HWR)                                           \
  {                                                                        \
    if (uact) {                                                            \
      uint2 gcurr = GREG;                                                  \
      int nr = ((T) + 2 < TT) ? (T) + 2 : (TT - 1);                        \
      GREG = ((const uint2*)(gbase + (size_t)nr * 400))[j];                \
      const unsigned int* hp = (HRD) + 28 * s2;                            \
      uint4 u0 = *((const uint4*)hp);                                      \
      uint4 u1 = *((const uint4*)(hp + 4));                                \
      uint4 u2 = *((const uint4*)(hp + 8));                                \
      uint4 u3 = *((const uint4*)(hp + 12));                               \
      uint4 u4 = *((const uint4*)(hp + 16));                               \
      uint4 u5 = *((const uint4*)(hp + 20));                               \
      unsigned int u6 = hp[24];                                            \
      float p0 = 0.f, p1 = 0.f, p2 = 0.f, p3 = 0.f;                        \
      SD2(0, u0.x)  SD2(1, u0.y)  SD2(2, u0.z)  SD2(3, u0.w)               \
      SD2(4, u1.x)  SD2(5, u1.y)  SD2(6, u1.z)  SD2(7, u1.w)               \
      SD2(8, u2.x)  SD2(9, u2.y)  SD2(10, u2.z) SD2(11, u2.w)              \
      SD2(12, u3.x) SD2(13, u3.y) SD2(14, u3.z) SD2(15, u3.w)              \
      SD2(16, u4.x) SD2(17, u4.y) SD2(18, u4.z) SD2(19, u4.w)              \
      SD2(20, u5.x) SD2(21, u5.y) SD2(22, u5.z) SD2(23, u5.w)              \
      SD2(24, u6)                                                          \
      p0 = qadd<177>(p0); p1 = qadd<177>(p1);                              \
      p2 = qadd<177>(p2); p3 = qadd<177>(p3);                              \
      h2_t glo = bc_h2(gcurr.x), ghi = bc_h2(gcurr.y);                     \
      float gi = p0 + bias0 + (float)glo[0];                               \
      float gf = p1 + bias1 + (float)glo[1];                               \
      float gg = p2 + bias2 + (float)ghi[0];                               \
      float go = p3 + bias3 + (float)ghi[1];                               \
      float iv = sigmoid_f(gi);                                            \
      float fv = sigmoid_f(gf);                                            \
      float gv = tanh_f(gg);                                               \
      float ov = sigmoid_f(go);                                            \
      c = fmaf(fv, c, iv * gv);                                            \
      float hvv = ov * tanh_f(c);                                          \
      float hnb = qbcast<2>(hvv);                                          \
      if ((tid & 3) == 0) {                                                \
        int k = tid >> 2;                                                  \
        unsigned int val = pk_rte(hvv, hnb);                               \
        (HWR)[k + (k >= 25 ? 3 : 0)] = val;                                \
        int ta = dir ? (TT - 1 - (T)) : (T);                               \
        ghb[(size_t)ta * 50 + k] = val;                                    \
      }                                                                    \
    }                                                                      \
    lds_barrier();                                                         \
  }

  for (int t2 = 0; t2 < TT; t2 += 2) {
    SSTEP(t2,     ga, hls0, hls1)
    SSTEP(t2 + 1, gb, hls1, hls0)
  }
#undef SSTEP
#undef SD2
}

// ===========================================================================
// emit_sum — em[b][t][25] = h_f.Wf^T + h_b.Wb^T + b_tag via MFMA (k=256
// padded concat: [hf 100 | 0 x28 | hb 100 | 0 x28]).
// Grid 1024 = (b 128) x (t-chunk 8 of 64); 256 thr; wave w -> 16 t-rows.
// ===========================================================================
__global__ __launch_bounds__(256, 1) void emit_sum(
    const float* __restrict__ w_tag, const float* __restrict__ b_tag,
    float* __restrict__ em)
{
  const int tid = threadIdx.x;
  const int b   = blockIdx.x >> 3;
  const int tc  = blockIdx.x & 7;
  const int t0  = tc * 64;

  __shared__ __align__(16) unsigned short hb[64][256];   // 32 KB

  const int wv   = tid >> 6;
  const int lane = tid & 63;
  const int l16  = lane & 15;
  const int quad = lane >> 4;

  // ---- B fragments: w_tag in padded-256 k-layout ----
  v8h wt[2][8];
  float eb[2];
#pragma unroll
  for (int lt = 0; lt < 2; ++lt) {
    const int label = lt * 16 + l16;
    const bool valid = label < LL;
    const float* wr = w_tag + (size_t)(valid ? label : 0) * 200;
#pragma unroll
    for (int kc = 0; kc < 8; ++kc) {
      float v[8];
#pragma unroll
      for (int e = 0; e < 8; ++e) {
        int k = kc * 32 + quad * 8 + e;
        float x = 0.f;
        if (valid) {
          if (k < 100) x = wr[k];
          else if (k >= 128 && k < 228) x = wr[k - 28];
        }
        v[e] = x;
      }
      uint4 u;
      u.x = pk(v[0], v[1]); u.y = pk(v[2], v[3]);
      u.z = pk(v[4], v[5]); u.w = pk(v[6], v[7]);
      wt[lt][kc] = __builtin_bit_cast(v8h, u);
    }
    eb[lt] = valid ? b_tag[label] : 0.f;
  }

  // ---- zero hb, then stage h rows (both dirs) ----
  {
    uint4 z = {0u, 0u, 0u, 0u};
    for (int i = tid; i < 2048; i += 256) ((uint4*)hb)[i] = z;
  }
  __syncthreads();
  for (int i = tid; i < 64 * 2 * 13; i += 256) {
    int row = i / 13, cp = i - 13 * row;
    int t = row >> 1, d = row & 1;
    const unsigned int* src = g_h2 +
        ((size_t)(d * BB + b) * TT + t0 + t) * 50 + cp * 4;
    char* dst = (char*)hb + t * 512 + d * 256 + cp * 16;
    if (cp < 12) *(uint4*)dst = *(const uint4*)src;
    else         *(uint2*)dst = *(const uint2*)src;
  }
  __syncthreads();

  // ---- compute: wave wv -> t rows t0+16*wv .. +15 ----
  const unsigned short* hr = &hb[16 * wv + l16][0];
  v8h ha[8];
#pragma unroll
  for (int kc = 0; kc < 8; ++kc)
    ha[kc] = LD8(hr, kc * 32 + quad * 8);

#pragma unroll
  for (int lt = 0; lt < 2; ++lt) {
    v4f acc = {0.f, 0.f, 0.f, 0.f};
#pragma unroll
    for (int kc = 0; kc < 8; ++kc)
      acc = MF(ha[kc], wt[lt][kc], acc);
    const int label = lt * 16 + l16;
    if (label < LL) {
#pragma unroll
      for (int r = 0; r < 4; ++r) {
        int t = t0 + 16 * wv + quad * 4 + r;
        em[((size_t)b * TT + t) * LL + label] = acc[r] + eb[lt];
      }
    }
  }
}

// ===========================================================================
// CRF — parallel chunked scan on summed em (round-5 versions, verified).
// ===========================================================================
#define CHN  8
#define CLEN 64
__device__ __align__(16) float g_PT[(size_t)BB * CHN * LL * 28];  // 2.87 MB

__global__ __launch_bounds__(128, 2) void crf_chunks(
    const float* __restrict__ em, const float* __restrict__ trans)
{
  const int tid = threadIdx.x;
  const int b   = blockIdx.x >> 3;
  const int c   = blockIdx.x & 7;
  const int ts  = c * CLEN;

  __shared__ __align__(16) float Al[2][LL][28];
  __shared__ __align__(16) float el[CLEN][32];

  {
    const int row  = tid >> 1;
    const int half = tid & 1;
    const int jb   = half ? 13 : 0;
    const int nj   = half ? 12 : 13;
    const float* pe = em + ((size_t)b * TT + ts + row) * LL;
    for (int q = 0; q < nj; ++q) {
      int jj = jb + q;
      el[row][jj] = fexp2(pe[jj] * F_LOG2E);
    }
  }

  const bool lact = tid < 125;
  const int i  = tid / 5;
  const int jg = tid - 5 * i;
  const int j0 = 5 * jg;

  float E[25][5];
  if (lact) {
#pragma unroll
    for (int k = 0; k < 25; ++k) {
      const float* tr = trans + k * 25 + j0;
#pragma unroll
      for (int u = 0; u < 5; ++u)
        E[k][u] = fexp2(tr[u] * F_LOG2E - 5.f);
    }
#pragma unroll
    for (int u = 0; u < 5; ++u)
      Al[0][i][j0 + u] = (i == j0 + u) ? 1.f : 0.f;
  }
  __syncthreads();

  int p = 0;
  const int s0 = (c == 0) ? 1 : 0;
  for (int st = s0; st < CLEN; ++st) {
    if (lact) {
      const float* ar = &Al[p][i][0];
      float4 q0 = *(const float4*)(ar);
      float4 q1 = *(const float4*)(ar + 4);
      float4 q2 = *(const float4*)(ar + 8);
      float4 q3 = *(const float4*)(ar + 12);
      float4 q4 = *(const float4*)(ar + 16);
      float4 q5 = *(const float4*)(ar + 20);
      float a24 = ar[24];
      float e0 = el[st][j0];
      float e1 = el[st][j0 + 1];
      float e2 = el[st][j0 + 2];
      float e3 = el[st][j0 + 3];
      float e4 = el[st][j0 + 4];
      float av[25] = {q0.x, q0.y, q0.z, q0.w, q1.x, q1.y, q1.z, q1.w,
                      q2.x, q2.y, q2.z, q2.w, q3.x, q3.y, q3.z, q3.w,
                      q4.x, q4.y, q4.z, q4.w, q5.x, q5.y, q5.z, q5.w, a24};
      float c0 = 0.f, c1 = 0.f, c2 = 0.f, c3 = 0.f, c4 = 0.f;
#pragma unroll
      for (int k = 0; k < 25; ++k) {
        float avk = av[k];
        c0 = fmaf(avk, E[k][0], c0);
        c1 = fmaf(avk, E[k][1], c1);
        c2 = fmaf(avk, E[k][2], c2);
        c3 = fmaf(avk, E[k][3], c3);
        c4 = fmaf(avk, E[k][4], c4);
      }
      float* wr = &Al[p ^ 1][i][j0];
      wr[0] = c0 * e0; wr[1] = c1 * e1; wr[2] = c2 * e2;
      wr[3] = c3 * e3; wr[4] = c4 * e4;
    }
    __syncthreads();
    p ^= 1;
  }

  if (lact) {
    const size_t base = ((size_t)(b * CHN + c)) * LL;
#pragma unroll
    for (int u = 0; u < 5; ++u)
      g_PT[(base + (j0 + u)) * 28 + i] = Al[p][i][j0 + u];
  }
}

__global__ __launch_bounds__(128) void crf_combine(
    const float* __restrict__ em,
    const int* __restrict__ tags, const int* __restrict__ lengths,
    const float* __restrict__ trans,
    const float* __restrict__ startt, const float* __restrict__ endt,
    float* __restrict__ out)
{
  const int tid = threadIdx.x;
  const int b   = blockIdx.x;

  __shared__ __align__(16) float Vs[28];

  if (tid < 64) {
    const int lane = tid;
    const int j = (lane < LL) ? lane : 0;
    const float* e0p = em + (size_t)b * TT * LL;
    float v = fexp2((startt[j] + e0p[j]) * F_LOG2E);
    float C = 0.f;
    for (int c = 0; c < CHN; ++c) {
      if (lane < LL) Vs[lane] = v;
      wave_fence();
      float4 s0 = *(const float4*)(Vs);
      float4 s1 = *(const float4*)(Vs + 4);
      float4 s2 = *(const float4*)(Vs + 8);
      float4 s3 = *(const float4*)(Vs + 12);
      float4 s4 = *(const float4*)(Vs + 16);
      float4 s5 = *(const float4*)(Vs + 20);
      float s24 = Vs[24];
      wave_fence();
      const float* pr = g_PT + ((size_t)(b * CHN + c) * LL + j) * 28;
      float4 p0 = *(const float4*)(pr);
      float4 p1 = *(const float4*)(pr + 4);
      float4 p2 = *(const float4*)(pr + 8);
      float4 p3 = *(const float4*)(pr + 12);
      float4 p4 = *(const float4*)(pr + 16);
      float4 p5 = *(const float4*)(pr + 20);
      float p24 = pr[24];
      float nv = s0.x * p0.x;
      nv = fmaf(s0.y, p0.y, nv); nv = fmaf(s0.z, p0.z, nv); nv = fmaf(s0.w, p0.w, nv);
      nv = fmaf(s1.x, p1.x, nv); nv = fmaf(s1.y, p1.y, nv);
      nv = fmaf(s1.z, p1.z, nv); nv = fmaf(s1.w, p1.w, nv);
      nv = fmaf(s2.x, p2.x, nv); nv = fmaf(s2.y, p2.y, nv);
      nv = fmaf(s2.z, p2.z, nv); nv = fmaf(s2.w, p2.w, nv);
      nv = fmaf(s3.x, p3.x, nv); nv = fmaf(s3.y, p3.y, nv);
      nv = fmaf(s3.z, p3.z, nv); nv = fmaf(s3.w, p3.w, nv);
      nv = fmaf(s4.x, p4.x, nv); nv = fmaf(s4.y, p4.y, nv);
      nv = fmaf(s4.z, p4.z, nv); nv = fmaf(s4.w, p4.w, nv);
      nv = fmaf(s5.x, p5.x, nv); nv = fmaf(s5.y, p5.y, nv);
      nv = fmaf(s5.z, p5.z, nv); nv = fmaf(s5.w, p5.w, nv);
      nv = fmaf(s24, p24, nv);
      float nv0 = rfl(nv);
      int k = ((__builtin_bit_cast(int, nv0) >> 23) & 255) - 127;
      k = (k > 100) ? 100 : ((k < -100) ? -100 : k);
      float scl = __builtin_bit_cast(float, (127 - k) << 23);
      v = nv * scl;
      C += (float)k;
    }
    float term = (lane < LL) ? v * fexp2(endt[j] * F_LOG2E) : 0.f;
    for (int o = 32; o > 0; o >>= 1) term += __shfl_down(term, o);
    if (lane == 0)
      atomicAdd(out, (flog2(term) + C + 5.f * 511.f) * F_LN2);
  } else {
    const int lane = tid & 63;
    const int len = lengths[b];
    float acc = 0.f;
#pragma unroll
    for (int k = 0; k < 8; ++k) {
      int t = k * 64 + lane;
      int tg = tags[b * TT + t];
      size_t ei = ((size_t)b * TT + t) * LL + tg;
      float e = em[ei];
      float term;
      if (t == 0) term = startt[tg] + e;
      else        term = trans[tags[b * TT + t - 1] * LL + tg] + e;
      if (t == len - 1) term += endt[tg];
      if (t < len) acc += term;
    }
    for (int o = 32; o > 0; o >>= 1) acc += __shfl_down(acc, o);
    if (lane == 0) atomicAdd(out, -acc);
  }
}

extern "C" void kernel_launch(void* const* d_in, const int* in_sizes, int n_in,
                              void* d_out, int out_size, void* d_ws, size_t ws_size,
                              hipStream_t stream) {
  const int*   tok   = (const int*)d_in[0];
  const int*   tags  = (const int*)d_in[1];
  const int*   lens  = (const int*)d_in[2];
  const float* emb   = (const float*)d_in[3];
  const float* wif   = (const float*)d_in[4];
  const float* whf   = (const float*)d_in[5];
  const float* bif   = (const float*)d_in[6];
  const float* bhf   = (const float*)d_in[7];
  const float* wib   = (const float*)d_in[8];
  const float* whb   = (const float*)d_in[9];
  const float* bib   = (const float*)d_in[10];
  const float* bhb   = (const float*)d_in[11];
  const float* wtag  = (const float*)d_in[12];
  const float* btag  = (const float*)d_in[13];
  const float* trans = (const float*)d_in[14];
  const float* st    = (const float*)d_in[15];
  const float* en    = (const float*)d_in[16];

  float* em = (float*)d_ws;   // 128*512*25*4 = 6,553,600 B (summed emissions)

  hipMemsetAsync(d_out, 0, sizeof(float), stream);

  gin_gemm<<<256, 512, 0, stream>>>(tok, emb, wif, wib);
  scan_lean<<<256, 256, 0, stream>>>(whf, whb, bif, bhf, bib, bhb);
  emit_sum<<<1024, 256, 0, stream>>>(wtag, btag, em);
  crf_chunks<<<BB * CHN, 128, 0, stream>>>(em, trans);
  crf_combine<<<BB, 128, 0, stream>>>(em, tags, lens, trans, st, en,
                                      (float*)d_out);
}

// Round 7
// 410.032 us; speedup vs baseline: 2.0701x; 1.2004x over previous
//
#include <hip/hip_runtime.h>
#include <cstdint>
#include <cstddef>

#define BB 128
#define TT 512
#define DD 100
#define HH 100
#define NG 400   // 4*H
#define LL 25
#define TS 32    // scan tile (steps per burst)
#define NTILE 16
#define F_LOG2E 1.44269504088896340736f
#define F_LN2   0.69314718055994530942f

typedef __decltype(__builtin_amdgcn_cvt_pkrtz(0.f, 0.f)) h2_t;
typedef _Float16 v8h __attribute__((ext_vector_type(8)));
typedef float v4f __attribute__((ext_vector_type(4)));

__device__ __forceinline__ h2_t bc_h2(unsigned int u) {
  return __builtin_bit_cast(h2_t, u);
}
__device__ __forceinline__ unsigned int pk(float x, float y) {
  return __builtin_bit_cast(unsigned int, __builtin_amdgcn_cvt_pkrtz(x, y));
}
// round-to-nearest-even fp16 pack (matches scalar (__fp16) h-store numerics)
__device__ __forceinline__ unsigned int pk_rte(float x, float y) {
  unsigned short a = __builtin_bit_cast(unsigned short, (__fp16)x);
  unsigned short c = __builtin_bit_cast(unsigned short, (__fp16)y);
  return (unsigned int)a | ((unsigned int)c << 16);
}

__device__ __forceinline__ float fdot2(h2_t a, h2_t b, float c) {
#if __has_builtin(__builtin_amdgcn_fdot2)
  return __builtin_amdgcn_fdot2(a, b, c, false);
#else
  return c + (float)a[0] * (float)b[0] + (float)a[1] * (float)b[1];
#endif
}

__device__ __forceinline__ float fexp2(float x) { return __builtin_amdgcn_exp2f(x); }
__device__ __forceinline__ float flog2(float x) { return __builtin_amdgcn_logf(x); }
__device__ __forceinline__ float frcp(float x)  { return __builtin_amdgcn_rcpf(x); }

__device__ __forceinline__ float sigmoid_f(float x) {
  return frcp(1.f + fexp2(-F_LOG2E * x));
}
__device__ __forceinline__ float tanh_f(float x) {
  float e = fexp2(2.f * F_LOG2E * x);
  return 1.f - 2.f * frcp(e + 1.f);
}

template <int CTRL>
__device__ __forceinline__ float qadd(float v) {
#if __has_builtin(__builtin_amdgcn_mov_dpp)
  int m = __builtin_amdgcn_mov_dpp(__builtin_bit_cast(int, v), CTRL, 0xF, 0xF, true);
  return v + __builtin_bit_cast(float, m);
#else
  int x = (CTRL == 177) ? 1 : 2;
  return v + __shfl_xor(v, x);
#endif
}

template <int LANE>
__device__ __forceinline__ float qbcast(float v) {
#if __has_builtin(__builtin_amdgcn_mov_dpp)
  int m = __builtin_amdgcn_mov_dpp(__builtin_bit_cast(int, v), LANE * 0x55, 0xF, 0xF, true);
  return __builtin_bit_cast(float, m);
#else
  return __shfl(v, (threadIdx.x & 63 & ~3) + LANE);
#endif
}

__device__ __forceinline__ float rfl(float v) {
  return __builtin_bit_cast(float,
      __builtin_amdgcn_readfirstlane(__builtin_bit_cast(int, v)));
}

__device__ __forceinline__ void wave_fence() {
#if __has_builtin(__builtin_amdgcn_wave_barrier)
  __builtin_amdgcn_wave_barrier();
#endif
}

// LDS-visibility-only barrier (vmcnt left free): imm 0xC07F.
__device__ __forceinline__ void lds_barrier() {
  __builtin_amdgcn_s_waitcnt(0xC07F);
  __builtin_amdgcn_s_barrier();
}

// ---------------------------------------------------------------------------
// FUSED BiLSTM + x-GEMM + emissions (v4 structure — verified 273 us).
// SINGLE change this round: __launch_bounds__(512,1) (was (512,2)).
// Rationale: VGPR_Count was pinned at the 128 cap while the per-wave union
// (wG 100 + step temps ~25 + bfr 64 + etag 16 + misc) is ~200 -> the
// allocator was forced to spill HOT scan registers to scratch, reloaded
// every one of the 512 serial steps. Cap 256 removes the forced hot spill;
// occupancy is unchanged in practice (256 blocks on 256 CUs = 1 block/CU).
// Also zeroes d_out (removes the separate memset node).
// ---------------------------------------------------------------------------
__global__ __launch_bounds__(512, 1) void lstm_fused4(
    const int* __restrict__ tok, const float* __restrict__ emb,
    const float* __restrict__ w_ih_f, const float* __restrict__ w_ih_b,
    const float* __restrict__ b_ih_f, const float* __restrict__ b_hh_f,
    const float* __restrict__ b_ih_b, const float* __restrict__ b_hh_b,
    const float* __restrict__ w_hh_f, const float* __restrict__ w_hh_b,
    const float* __restrict__ w_tag, const float* __restrict__ b_tag,
    float* __restrict__ em_f, float* __restrict__ em_b,
    float* __restrict__ out_zero)
{
  const int tid = threadIdx.x;
  const int b   = blockIdx.x & 127;
  const int dir = blockIdx.x >> 7;
  if (blockIdx.x == 0 && tid == 0) *out_zero = 0.f;
  const float* w_hh = dir ? w_hh_b : w_hh_f;
  const float* w_ih = dir ? w_ih_b : w_ih_f;
  const float* b_ih = dir ? b_ih_b : b_ih_f;
  const float* b_hh = dir ? b_hh_b : b_hh_f;
  float* emo = dir ? em_b : em_f;

  __shared__ __align__(16) unsigned short gin_lds[TS * 400];   // 25.6 KB
  __shared__ __align__(16) unsigned int xlds[TS * 68];         // 8.7 KB
  __shared__ __align__(16) unsigned int hhist[TS * 68];        // 8.7 KB (h history)
  __shared__ __align__(16) unsigned int hls0[56];
  __shared__ __align__(16) unsigned int hls1[56];

  // burst lane mapping
  const int wv   = tid >> 6;
  const int lane = tid & 63;
  const int l16  = lane & 15;
  const int quad = lane >> 4;
  const int c0b  = (25 * wv) >> 3;
  const int c1b  = (25 * (wv + 1)) >> 3;
  const int ncol = c1b - c0b;   // 3 or 4

  // ---- one-time: B fragments from global w_ih into registers ----
  v8h bfr[4][4];
  int pcol[4];
#pragma unroll
  for (int ci = 0; ci < 4; ++ci) {
    const int cc = (ci < ncol) ? (c0b + ci) : c0b;
    const int n  = 16 * cc + l16;
    const float* wr = w_ih + (size_t)n * DD;
#pragma unroll
    for (int f = 0; f < 3; ++f) {
      const float* wp = wr + f * 32 + quad * 8;
      float4 va = *(const float4*)(wp);
      float4 vb = *(const float4*)(wp + 4);
      uint4 u;
      u.x = pk(va.x, va.y); u.y = pk(va.z, va.w);
      u.z = pk(vb.x, vb.y); u.w = pk(vb.z, vb.w);
      bfr[ci][f] = __builtin_bit_cast(v8h, u);
    }
    {
      uint4 u = {0u, 0u, 0u, 0u};
      if (quad == 0) {
        float4 va = *(const float4*)(wr + 96);
        u.x = pk(va.x, va.y); u.y = pk(va.z, va.w);
      }
      bfr[ci][3] = __builtin_bit_cast(v8h, u);
    }
    const int qn = (n * 41) >> 12;            // n/100 for n<400
    pcol[ci] = ((n - 100 * qn) << 2) + qn;    // store permutation
  }

  // ---- xlds / hhist K-pad zero ----
  for (int i = tid; i < TS * 18; i += 512) {
    int row = i / 18;
    int d = i - row * 18;
    xlds[row * 68 + 50 + d] = 0u;
    hhist[row * 68 + 50 + d] = 0u;
  }

  // ---- scan state: waves 0-3, lane = 2*j + s2 ----
  const bool uact = tid < 200;
  const int j  = tid >> 1;
  const int s2 = tid & 1;

  h2_t wG0[25], wG1[25], wG2[25], wG3[25];
  float bias0 = 0.f, bias1 = 0.f, bias2 = 0.f, bias3 = 0.f;
  if (uact) {
    const float* r0 = w_hh + (size_t)(0 * 100 + j) * HH + 50 * s2;
    const float* r1 = w_hh + (size_t)(1 * 100 + j) * HH + 50 * s2;
    const float* r2 = w_hh + (size_t)(2 * 100 + j) * HH + 50 * s2;
    const float* r3 = w_hh + (size_t)(3 * 100 + j) * HH + 50 * s2;
#pragma unroll
    for (int d = 0; d < 25; ++d) {
      float2 v0 = *(const float2*)(r0 + 2 * d);
      float2 v1 = *(const float2*)(r1 + 2 * d);
      float2 v2 = *(const float2*)(r2 + 2 * d);
      float2 v3 = *(const float2*)(r3 + 2 * d);
      wG0[d] = __builtin_amdgcn_cvt_pkrtz(v0.x, v0.y);
      wG1[d] = __builtin_amdgcn_cvt_pkrtz(v1.x, v1.y);
      wG2[d] = __builtin_amdgcn_cvt_pkrtz(v2.x, v2.y);
      wG3[d] = __builtin_amdgcn_cvt_pkrtz(v3.x, v3.y);
    }
    bias0 = b_ih[j]       + b_hh[j];
    bias1 = b_ih[100 + j] + b_hh[100 + j];
    bias2 = b_ih[200 + j] + b_hh[200 + j];
    bias3 = b_ih[300 + j] + b_hh[300 + j];
  }

  // ---- emission GEMM state: waves 4-7 ----
  const int ew    = wv - 4;
  const int ecb   = ew & 1;          // label col-block (0: l 0-15, 1: l 16-24)
  const int erg   = (ew >> 1) & 1;   // step row-group (0: 0-15, 1: 16-31)
  const int encol = 16 * ecb + l16;  // output label index
  const bool eact2 = (wv >= 4) && (encol < LL);
  v8h etag[4];
  float ebias = 0.f;
  if (wv >= 4) {
#pragma unroll
    for (int f = 0; f < 3; ++f) {
      uint4 u = {0u, 0u, 0u, 0u};
      if (eact2) {
        const float* wp = w_tag + (size_t)encol * 200 + dir * 100 + f * 32 + quad * 8;
        float4 va = *(const float4*)(wp);
        float4 vb = *(const float4*)(wp + 4);
        u.x = pk(va.x, va.y); u.y = pk(va.z, va.w);
        u.z = pk(vb.x, vb.y); u.w = pk(vb.z, vb.w);
      }
      etag[f] = __builtin_bit_cast(v8h, u);
    }
    {
      uint4 u = {0u, 0u, 0u, 0u};
      if (eact2 && quad == 0) {
        float4 va = *(const float4*)(w_tag + (size_t)encol * 200 + dir * 100 + 96);
        u.x = pk(va.x, va.y); u.y = pk(va.z, va.w);
      }
      etag[3] = __builtin_bit_cast(v8h, u);
    }
    if (eact2 && dir == 0) ebias = b_tag[encol];
  }

  if (tid < 56) { hls0[tid] = 0u; hls1[tid] = 0u; }

  // x staging mapping: thread t<416 covers (row = t/13, seg = t%13)
  const int tprow = tid / 13;
  const int tps   = tid - 13 * tprow;
  const bool tp_act = tid < 416;

  // initial x prefetch (tile 0)
  float4 xa = {0, 0, 0, 0}, xb = {0, 0, 0, 0};
  if (tp_act) {
    int ii = tprow;
    int tt = dir ? (TT - 1 - ii) : ii;
    int tk = tok[b * TT + tt];
    const float* xp = emb + (size_t)tk * DD + 8 * tps;
    xa = *(const float4*)xp;
    if (tps < 12) xb = *(const float4*)(xp + 4);
  }

  float c = 0.f;
  uint2 gnext = {0u, 0u};

#define SD2(d, hw) { h2_t hv = bc_h2(hw);                                  \
  p0 = fdot2(wG0[d], hv, p0); p1 = fdot2(wG1[d], hv, p1);                  \
  p2 = fdot2(wG2[d], hv, p2); p3 = fdot2(wG3[d], hv, p3); }

#define SCAN2(HRD, HWR, ROW)                                               \
  {                                                                        \
    if (uact) {                                                            \
      uint2 gcurr = gnext;                                                 \
      int nr = ((ROW) < TS - 1) ? (ROW) + 1 : TS - 1;                      \
      gnext = ((const uint2*)(gin_lds + nr * 400))[j];                     \
      const unsigned int* hp = (HRD) + 28 * s2;                            \
      uint4 u0 = *((const uint4*)hp);                                      \
      uint4 u1 = *((const uint4*)(hp + 4));                                \
      uint4 u2 = *((const uint4*)(hp + 8));                                \
      uint4 u3 = *((const uint4*)(hp + 12));                               \
      uint4 u4 = *((const uint4*)(hp + 16));                               \
      uint4 u5 = *((const uint4*)(hp + 20));                               \
      unsigned int u6 = hp[24];                                            \
      float p0 = 0.f, p1 = 0.f, p2 = 0.f, p3 = 0.f;                        \
      SD2(0, u0.x)  SD2(1, u0.y)  SD2(2, u0.z)  SD2(3, u0.w)               \
      SD2(4, u1.x)  SD2(5, u1.y)  SD2(6, u1.z)  SD2(7, u1.w)               \
      SD2(8, u2.x)  SD2(9, u2.y)  SD2(10, u2.z) SD2(11, u2.w)              \
      SD2(12, u3.x) SD2(13, u3.y) SD2(14, u3.z) SD2(15, u3.w)              \
      SD2(16, u4.x) SD2(17, u4.y) SD2(18, u4.z) SD2(19, u4.w)              \
      SD2(20, u5.x) SD2(21, u5.y) SD2(22, u5.z) SD2(23, u5.w)              \
      SD2(24, u6)                                                          \
      p0 = qadd<177>(p0); p1 = qadd<177>(p1);                              \
      p2 = qadd<177>(p2); p3 = qadd<177>(p3);                              \
      h2_t glo = bc_h2(gcurr.x), ghi = bc_h2(gcurr.y);                     \
      float gi = p0 + bias0 + (float)glo[0];                               \
      float gf = p1 + bias1 + (float)glo[1];                               \
      float gg = p2 + bias2 + (float)ghi[0];                               \
      float go = p3 + bias3 + (float)ghi[1];                               \
      float iv = sigmoid_f(gi);                                            \
      float fv = sigmoid_f(gf);                                            \
      float gv = tanh_f(gg);                                               \
      float ov = sigmoid_f(go);                                            \
      c = fmaf(fv, c, iv * gv);                                            \
      float hvv = ov * tanh_f(c);                                          \
      float hnb = qbcast<2>(hvv);                                          \
      if ((tid & 3) == 0) {                                                \
        int k = tid >> 2;                                                  \
        unsigned int val = pk_rte(hvv, hnb);                               \
        (HWR)[k + (k >= 25 ? 3 : 0)] = val;                                \
        hhist[(ROW) * 68 + k] = val;                                       \
      }                                                                    \
    }                                                                      \
    lds_barrier();                                                         \
  }

#define EMIT_GEMM(TB)                                                      \
  {                                                                        \
    const unsigned int* hb = hhist + (erg * 16 + l16) * 68 + quad * 4;     \
    v8h ah0 = __builtin_bit_cast(v8h, *(const uint4*)(hb));                \
    v8h ah1 = __builtin_bit_cast(v8h, *(const uint4*)(hb + 16));           \
    v8h ah2 = __builtin_bit_cast(v8h, *(const uint4*)(hb + 32));           \
    v8h ah3 = __builtin_bit_cast(v8h, *(const uint4*)(hb + 48));           \
    v4f ea = {0.f, 0.f, 0.f, 0.f};                                         \
    ea = __builtin_amdgcn_mfma_f32_16x16x32_f16(ah0, etag[0], ea, 0, 0, 0);\
    ea = __builtin_amdgcn_mfma_f32_16x16x32_f16(ah1, etag[1], ea, 0, 0, 0);\
    ea = __builtin_amdgcn_mfma_f32_16x16x32_f16(ah2, etag[2], ea, 0, 0, 0);\
    ea = __builtin_amdgcn_mfma_f32_16x16x32_f16(ah3, etag[3], ea, 0, 0, 0);\
    if (eact2) {                                                           \
      const int tb = (TB) + erg * 16 + quad * 4;                           \
      _Pragma("unroll")                                                    \
      for (int r = 0; r < 4; ++r) {                                        \
        int t = dir ? (TT - 1 - (tb + r)) : (tb + r);                      \
        emo[((size_t)b * TT + t) * LL + encol] = ea[r] + ebias;            \
      }                                                                    \
    }                                                                      \
  }

  __syncthreads();  // pads / hls init complete

  for (int T = 0; T < NTILE; ++T) {
    // ---- write prefetched x regs to xlds ----
    if (tp_act) {
      unsigned int* xr = xlds + tprow * 68 + 4 * tps;
      if (tps < 12) {
        uint4 u;
        u.x = pk(xa.x, xa.y); u.y = pk(xa.z, xa.w);
        u.z = pk(xb.x, xb.y); u.w = pk(xb.z, xb.w);
        *(uint4*)xr = u;
      } else {
        xr[0] = pk(xa.x, xa.y);
        xr[1] = pk(xa.z, xa.w);
      }
    }
    __syncthreads();

    // ---- BURST ----
    {
      v8h af[2][4];
#pragma unroll
      for (int rg = 0; rg < 2; ++rg)
#pragma unroll
        for (int f = 0; f < 4; ++f)
          af[rg][f] = __builtin_bit_cast(v8h,
              *(const uint4*)(xlds + (rg * 16 + l16) * 68 + f * 16 + quad * 4));

      // kick off next tile's x prefetch (stays in flight through the scan)
      if (tp_act && T + 1 < NTILE) {
        int ii = (T + 1) * TS + tprow;
        int tt = dir ? (TT - 1 - ii) : ii;
        int tk = tok[b * TT + tt];
        const float* xp = emb + (size_t)tk * DD + 8 * tps;
        xa = *(const float4*)xp;
        if (tps < 12) xb = *(const float4*)(xp + 4);
      }

      __fp16* gout = (__fp16*)gin_lds;
#pragma unroll
      for (int ci = 0; ci < 4; ++ci) {
        if (ci >= ncol) break;
        const int p = pcol[ci];
#pragma unroll
        for (int rg = 0; rg < 2; ++rg) {
          v4f acc = {0.f, 0.f, 0.f, 0.f};
          acc = __builtin_amdgcn_mfma_f32_16x16x32_f16(af[rg][0], bfr[ci][0], acc, 0, 0, 0);
          acc = __builtin_amdgcn_mfma_f32_16x16x32_f16(af[rg][1], bfr[ci][1], acc, 0, 0, 0);
          acc = __builtin_amdgcn_mfma_f32_16x16x32_f16(af[rg][2], bfr[ci][2], acc, 0, 0, 0);
          acc = __builtin_amdgcn_mfma_f32_16x16x32_f16(af[rg][3], bfr[ci][3], acc, 0, 0, 0);
          const int rowb = rg * 16 + quad * 4;
#pragma unroll
          for (int r = 0; r < 4; ++r)
            gout[(rowb + r) * 400 + p] = (__fp16)acc[r];
        }
      }

      // ---- emission GEMM for previous tile's h (waves 4-7) ----
      if (wv >= 4 && T > 0) {
        EMIT_GEMM((T - 1) * TS)
      }
    }
    __syncthreads();
    if (uact) gnext = ((const uint2*)gin_lds)[j];

    // ---- TS scan steps ----
    for (int it = 0; it < TS; it += 2) {
      SCAN2(hls0, hls1, it)
      SCAN2(hls1, hls0, it + 1)
    }
  }

  // epilogue: emissions for the final tile (hhist holds tile NTILE-1's h;
  // last scan step ended with lds_barrier, so it is visible)
  if (wv >= 4) {
    EMIT_GEMM((NTILE - 1) * TS)
  }
#undef EMIT_GEMM
#undef SCAN2
#undef SD2
}

// ===========================================================================
// CRF — parallel chunked scan (round-1 versions, verified).
// ===========================================================================
#define CHN  8
#define CLEN 64
__device__ __align__(16) float g_PT[(size_t)BB * CHN * LL * 28];  // 2.87 MB

__global__ __launch_bounds__(128, 2) void crf_chunks(
    const float* __restrict__ em_f, const float* __restrict__ em_b,
    const float* __restrict__ trans)
{
  const int tid = threadIdx.x;
  const int b   = blockIdx.x >> 3;
  const int c   = blockIdx.x & 7;
  const int ts  = c * CLEN;

  __shared__ __align__(16) float Al[2][LL][28];   // double-buffered A
  __shared__ __align__(16) float el[CLEN][32];    // e_t[j] = exp(em_t[j])

  // ---- stage e rows (2 threads per time step) ----
  {
    const int row  = tid >> 1;        // 0..63
    const int half = tid & 1;
    const int jb   = half ? 13 : 0;
    const int nj   = half ? 12 : 13;
    const float* pf = em_f + ((size_t)b * TT + ts + row) * LL;
    const float* pb = em_b + ((size_t)b * TT + ts + row) * LL;
    for (int q = 0; q < nj; ++q) {
      int jj = jb + q;
      el[row][jj] = fexp2((pf[jj] + pb[jj]) * F_LOG2E);
    }
  }

  const bool lact = tid < 125;
  const int i  = tid / 5;          // output row 0..24
  const int jg = tid - 5 * i;      // col group 0..4
  const int j0 = 5 * jg;

  // ---- E' = exp(T)*2^-5, columns j0..j0+4, in registers (125 VGPR) ----
  float E[25][5];
  if (lact) {
#pragma unroll
    for (int k = 0; k < 25; ++k) {
      const float* tr = trans + k * 25 + j0;
#pragma unroll
      for (int u = 0; u < 5; ++u)
        E[k][u] = fexp2(tr[u] * F_LOG2E - 5.f);
    }
    // A = I
#pragma unroll
    for (int u = 0; u < 5; ++u)
      Al[0][i][j0 + u] = (i == j0 + u) ? 1.f : 0.f;
  }
  __syncthreads();

  int p = 0;
  const int s0 = (c == 0) ? 1 : 0;   // chunk 0 covers t = 1..63
  for (int st = s0; st < CLEN; ++st) {
    if (lact) {
      const float* ar = &Al[p][i][0];
      float4 q0 = *(const float4*)(ar);
      float4 q1 = *(const float4*)(ar + 4);
      float4 q2 = *(const float4*)(ar + 8);
      float4 q3 = *(const float4*)(ar + 12);
      float4 q4 = *(const float4*)(ar + 16);
      float4 q5 = *(const float4*)(ar + 20);
      float a24 = ar[24];
      float e0 = el[st][j0];
      float e1 = el[st][j0 + 1];
      float e2 = el[st][j0 + 2];
      float e3 = el[st][j0 + 3];
      float e4 = el[st][j0 + 4];
      float av[25] = {q0.x, q0.y, q0.z, q0.w, q1.x, q1.y, q1.z, q1.w,
                      q2.x, q2.y, q2.z, q2.w, q3.x, q3.y, q3.z, q3.w,
                      q4.x, q4.y, q4.z, q4.w, q5.x, q5.y, q5.z, q5.w, a24};
      float c0 = 0.f, c1 = 0.f, c2 = 0.f, c3 = 0.f, c4 = 0.f;
#pragma unroll
      for (int k = 0; k < 25; ++k) {
        float avk = av[k];
        c0 = fmaf(avk, E[k][0], c0);
        c1 = fmaf(avk, E[k][1], c1);
        c2 = fmaf(avk, E[k][2], c2);
        c3 = fmaf(avk, E[k][3], c3);
        c4 = fmaf(avk, E[k][4], c4);
      }
      float* wr = &Al[p ^ 1][i][j0];
      wr[0] = c0 * e0; wr[1] = c1 * e1; wr[2] = c2 * e2;
      wr[3] = c3 * e3; wr[4] = c4 * e4;
    }
    __syncthreads();
    p ^= 1;
  }

  // ---- store P transposed: g_PT[(b*8+c)*25 + j][i], row stride 28 ----
  if (lact) {
    const size_t base = ((size_t)(b * CHN + c)) * LL;
#pragma unroll
    for (int u = 0; u < 5; ++u)
      g_PT[(base + (j0 + u)) * 28 + i] = Al[p][i][j0 + u];
  }
}

__global__ __launch_bounds__(128) void crf_combine(
    const float* __restrict__ em_f, const float* __restrict__ em_b,
    const int* __restrict__ tags, const int* __restrict__ lengths,
    const float* __restrict__ trans,
    const float* __restrict__ startt, const float* __restrict__ endt,
    float* __restrict__ out)
{
  const int tid = threadIdx.x;
  const int b   = blockIdx.x;

  __shared__ __align__(16) float Vs[28];

  if (tid < 64) {
    // -------- wave 0: logZ via chunk-matrix chain --------
    const int lane = tid;
    const int j = (lane < LL) ? lane : 0;
    const float* ef0 = em_f + (size_t)b * TT * LL;
    const float* eb0 = em_b + (size_t)b * TT * LL;
    float v = fexp2((startt[j] + ef0[j] + eb0[j]) * F_LOG2E);  // alpha0
    float C = 0.f;  // accumulated log2 scale
    for (int c = 0; c < CHN; ++c) {
      if (lane < LL) Vs[lane] = v;
      wave_fence();
      float4 s0 = *(const float4*)(Vs);
      float4 s1 = *(const float4*)(Vs + 4);
      float4 s2 = *(const float4*)(Vs + 8);
      float4 s3 = *(const float4*)(Vs + 12);
      float4 s4 = *(const float4*)(Vs + 16);
      float4 s5 = *(const float4*)(Vs + 20);
      float s24 = Vs[24];
      wave_fence();
      const float* pr = g_PT + ((size_t)(b * CHN + c) * LL + j) * 28;
      float4 p0 = *(const float4*)(pr);
      float4 p1 = *(const float4*)(pr + 4);
      float4 p2 = *(const float4*)(pr + 8);
      float4 p3 = *(const float4*)(pr + 12);
      float4 p4 = *(const float4*)(pr + 16);
      float4 p5 = *(const float4*)(pr + 20);
      float p24 = pr[24];
      float nv = s0.x * p0.x;
      nv = fmaf(s0.y, p0.y, nv); nv = fmaf(s0.z, p0.z, nv); nv = fmaf(s0.w, p0.w, nv);
      nv = fmaf(s1.x, p1.x, nv); nv = fmaf(s1.y, p1.y, nv);
      nv = fmaf(s1.z, p1.z, nv); nv = fmaf(s1.w, p1.w, nv);
      nv = fmaf(s2.x, p2.x, nv); nv = fmaf(s2.y, p2.y, nv);
      nv = fmaf(s2.z, p2.z, nv); nv = fmaf(s2.w, p2.w, nv);
      nv = fmaf(s3.x, p3.x, nv); nv = fmaf(s3.y, p3.y, nv);
      nv = fmaf(s3.z, p3.z, nv); nv = fmaf(s3.w, p3.w, nv);
      nv = fmaf(s4.x, p4.x, nv); nv = fmaf(s4.y, p4.y, nv);
      nv = fmaf(s4.z, p4.z, nv); nv = fmaf(s4.w, p4.w, nv);
      nv = fmaf(s5.x, p5.x, nv); nv = fmaf(s5.y, p5.y, nv);
      nv = fmaf(s5.z, p5.z, nv); nv = fmaf(s5.w, p5.w, nv);
      nv = fmaf(s24, p24, nv);
      // renormalize by lane-0 exponent (all entries same magnitude class)
      float nv0 = rfl(nv);
      int k = ((__builtin_bit_cast(int, nv0) >> 23) & 255) - 127;
      k = (k > 100) ? 100 : ((k < -100) ? -100 : k);
      float scl = __builtin_bit_cast(float, (127 - k) << 23);
      v = nv * scl;
      C += (float)k;
    }
    float term = (lane < LL) ? v * fexp2(endt[j] * F_LOG2E) : 0.f;
    for (int o = 32; o > 0; o >>= 1) term += __shfl_down(term, o);
    if (lane == 0)
      atomicAdd(out, (flog2(term) + C + 5.f * 511.f) * F_LN2);
  } else {
    // -------- wave 1: gold path score --------
    const int lane = tid & 63;
    const int len = lengths[b];
    float acc = 0.f;
#pragma unroll
    for (int k = 0; k < 8; ++k) {
      int t = k * 64 + lane;
      int tg = tags[b * TT + t];
      size_t ei = ((size_t)b * TT + t) * LL + tg;
      float e = em_f[ei] + em_b[ei];
      float term;
      if (t == 0) term = startt[tg] + e;
      else        term = trans[tags[b * TT + t - 1] * LL + tg] + e;
      if (t == len - 1) term += endt[tg];
      if (t < len) acc += term;
    }
    for (int o = 32; o > 0; o >>= 1) acc += __shfl_down(acc, o);
    if (lane == 0) atomicAdd(out, -acc);
  }
}

extern "C" void kernel_launch(void* const* d_in, const int* in_sizes, int n_in,
                              void* d_out, int out_size, void* d_ws, size_t ws_size,
                              hipStream_t stream) {
  const int*   tok   = (const int*)d_in[0];
  const int*   tags  = (const int*)d_in[1];
  const int*   lens  = (const int*)d_in[2];
  const float* emb   = (const float*)d_in[3];
  const float* wif   = (const float*)d_in[4];
  const float* whf   = (const float*)d_in[5];
  const float* bif   = (const float*)d_in[6];
  const float* bhf   = (const float*)d_in[7];
  const float* wib   = (const float*)d_in[8];
  const float* whb   = (const float*)d_in[9];
  const float* bib   = (const float*)d_in[10];
  const float* bhb   = (const float*)d_in[11];
  const float* wtag  = (const float*)d_in[12];
  const float* btag  = (const float*)d_in[13];
  const float* trans = (const float*)d_in[14];
  const float* st    = (const float*)d_in[15];
  const float* en    = (const float*)d_in[16];

  char* wsb = (char*)d_ws;
  float* em_f = (float*)wsb;                                   //  6,553,600 B
  float* em_b = (float*)(wsb + 6553600);                       //  6,553,600 B

  lstm_fused4<<<256, 512, 0, stream>>>(tok, emb, wif, wib, bif, bhf, bib, bhb,
                                       whf, whb, wtag, btag, em_f, em_b,
                                       (float*)d_out);
  crf_chunks<<<BB * CHN, 128, 0, stream>>>(em_f, em_b, trans);
  crf_combine<<<BB, 128, 0, stream>>>(em_f, em_b, tags, lens, trans, st, en,
                                      (float*)d_out);
}